// Round 1
// baseline (782.218 us; speedup 1.0000x reference)
//
#include <hip/hip_runtime.h>
#include <hip/hip_bf16.h>
#include <math.h>

// Problem constants
#define B_SZ   1024   // batch
#define D_SZ   512    // in_features
#define KC_SZ  256    // out_features (classes)
#define NLOW   130816 // 512*511/2

// Tile config
#define BM 128
#define BN 128
#define BK 32
#define LDA 40        // padded LDS stride (bf16 elems): 80 B = 20 banks -> uniform spread

typedef __attribute__((ext_vector_type(4))) float  f32x4;
typedef __attribute__((ext_vector_type(8))) __bf16 bf16x8;

// out[b,k] = || (x_b - w_k)^T L_k ||_2,  L_k lower-triangular:
//   L[d][e] = 0 (e>d), diag[d]^2 (e==d), lower[d*(d-1)/2 + e] (e<d)
// GEMM: D[b][e] = sum_d V[b][d] * L[d][e], then row-norm over e.
__global__ __launch_bounds__(256, 2)
void gml2_kernel(const float* __restrict__ X,
                 const float* __restrict__ W,
                 const float* __restrict__ Ldiag,
                 const float* __restrict__ Llow,
                 float* __restrict__ Out) {
    __shared__ __bf16 As[BM * LDA];
    __shared__ __bf16 Bs[BN * LDA];
    __shared__ float  osum[2][BM];

    const int tid  = threadIdx.x;
    const int bx   = blockIdx.x;
    const int kc   = bx >> 3;     // class index (8 consecutive blocks share kc -> L2/L3 reuse)
    const int mt   = bx & 7;      // row tile

    const int lane = tid & 63;
    const int wave = tid >> 6;
    const int wm   = (wave & 1) * 64;   // wave row offset in tile
    const int wn   = (wave >> 1) * 64;  // wave col offset in tile
    const int c    = lane & 15;
    const int q    = lane >> 4;

    // A staging: thread -> (row m, k-half)
    const int am  = tid >> 1;           // 0..127
    const int akh = (tid & 1) << 4;     // 0 or 16
    const float* xrow = X + (size_t)(mt * BM + am) * D_SZ;
    const float* wrow = W + (size_t)kc * D_SZ;

    // B staging: thread -> (col e, d-half)
    const int be = tid & 127;           // e within tile
    const int bd = (tid >> 7) << 4;     // 0 or 16
    const float* lowbase  = Llow  + (size_t)kc * NLOW;
    const float* diagbase = Ldiag + (size_t)kc * D_SZ;

    float rsum[16];
    #pragma unroll
    for (int i = 0; i < 16; ++i) rsum[i] = 0.f;

    for (int ct = 0; ct < 4; ++ct) {
        const int e0 = ct * BN;
        f32x4 acc[4][4];
        #pragma unroll
        for (int mi = 0; mi < 4; ++mi)
            #pragma unroll
            for (int ni = 0; ni < 4; ++ni)
                acc[mi][ni] = (f32x4){0.f, 0.f, 0.f, 0.f};

        // triangular skip: rows d < e0 of L contribute nothing to cols >= e0
        for (int k0 = e0; k0 < D_SZ; k0 += BK) {
            // ---- stage A: V = X - w, 128 rows x 32 k ----
            {
                const float* xp = xrow + k0 + akh;
                const float* wp = wrow + k0 + akh;
                f32x4 xs[4], ws4[4];
                #pragma unroll
                for (int i = 0; i < 4; ++i) xs[i]  = ((const f32x4*)xp)[i];
                #pragma unroll
                for (int i = 0; i < 4; ++i) ws4[i] = ((const f32x4*)wp)[i];
                bf16x8 p0, p1;
                #pragma unroll
                for (int i = 0; i < 4; ++i) {
                    #pragma unroll
                    for (int l = 0; l < 4; ++l) {
                        float v = xs[i][l] - ws4[i][l];
                        int idx = i * 4 + l;
                        if (idx < 8) p0[idx] = (__bf16)v;
                        else         p1[idx - 8] = (__bf16)v;
                    }
                }
                *(bf16x8*)&As[am * LDA + akh]     = p0;
                *(bf16x8*)&As[am * LDA + akh + 8] = p1;
            }
            // ---- stage B: Bs[e][d] = L[d][e], 32 d x 128 e, transposed in regs ----
            {
                const int e  = e0 + be;
                const int d0 = k0 + bd;
                float v[16];
                int tri = (d0 * (d0 - 1)) >> 1;   // d0*(d0-1)/2
                if (k0 >= e0 + BN) {
                    // fully below diagonal: every d > every e -> unconditional loads
                    #pragma unroll
                    for (int j = 0; j < 16; ++j) {
                        v[j] = lowbase[tri + e];
                        tri += d0 + j;            // tri(d+1) = tri(d) + d
                    }
                } else {
                    #pragma unroll
                    for (int j = 0; j < 16; ++j) {
                        const int d = d0 + j;
                        float val = 0.f;
                        if (d > e)       val = lowbase[tri + e];
                        else if (d == e) { float dq = diagbase[d]; val = dq * dq; }
                        v[j] = val;
                        tri += d;
                    }
                }
                bf16x8 p0, p1;
                #pragma unroll
                for (int j = 0; j < 8; ++j) { p0[j] = (__bf16)v[j]; p1[j] = (__bf16)v[j + 8]; }
                *(bf16x8*)&Bs[be * LDA + bd]     = p0;
                *(bf16x8*)&Bs[be * LDA + bd + 8] = p1;
            }
            __syncthreads();
            // ---- MFMA: 4x4 tiles of 16x16x32 per wave ----
            bf16x8 af[4], bfr[4];
            #pragma unroll
            for (int mi = 0; mi < 4; ++mi)
                af[mi] = *(const bf16x8*)&As[(wm + mi * 16 + c) * LDA + q * 8];
            #pragma unroll
            for (int ni = 0; ni < 4; ++ni)
                bfr[ni] = *(const bf16x8*)&Bs[(wn + ni * 16 + c) * LDA + q * 8];
            #pragma unroll
            for (int mi = 0; mi < 4; ++mi)
                #pragma unroll
                for (int ni = 0; ni < 4; ++ni)
                    acc[mi][ni] = __builtin_amdgcn_mfma_f32_16x16x32_bf16(
                        af[mi], bfr[ni], acc[mi][ni], 0, 0, 0);
            __syncthreads();
        }
        // epilogue for this col-tile: accumulate y^2 per row
        // C/D layout: col = lane&15, row = q*4 + reg
        #pragma unroll
        for (int mi = 0; mi < 4; ++mi)
            #pragma unroll
            for (int ni = 0; ni < 4; ++ni)
                #pragma unroll
                for (int r = 0; r < 4; ++r) {
                    float y = acc[mi][ni][r];
                    rsum[mi * 4 + r] += y * y;
                }
    }

    // reduce across the 16 col-lanes of each quad
    #pragma unroll
    for (int i = 0; i < 16; ++i) {
        float s = rsum[i];
        s += __shfl_xor(s, 1, 64);
        s += __shfl_xor(s, 2, 64);
        s += __shfl_xor(s, 4, 64);
        s += __shfl_xor(s, 8, 64);
        rsum[i] = s;
    }
    const int wnIdx = wave >> 1;
    if (c == 0) {
        #pragma unroll
        for (int mi = 0; mi < 4; ++mi)
            #pragma unroll
            for (int r = 0; r < 4; ++r)
                osum[wnIdx][wm + mi * 16 + q * 4 + r] = rsum[mi * 4 + r];
    }
    __syncthreads();
    if (tid < BM) {
        float s = osum[0][tid] + osum[1][tid];
        Out[(size_t)(mt * BM + tid) * KC_SZ + kc] = sqrtf(s);
    }
}

extern "C" void kernel_launch(void* const* d_in, const int* in_sizes, int n_in,
                              void* d_out, int out_size, void* d_ws, size_t ws_size,
                              hipStream_t stream) {
    const float* X  = (const float*)d_in[0];  // [1024, 512]
    const float* W  = (const float*)d_in[1];  // [256, 1, 512]
    const float* Ld = (const float*)d_in[2];  // [256, 512]
    const float* Ll = (const float*)d_in[3];  // [256, 130816]
    float* Out = (float*)d_out;               // [1024, 256]

    dim3 grid(KC_SZ * (B_SZ / BM));           // 2048 blocks
    dim3 block(256);
    gml2_kernel<<<grid, block, 0, stream>>>(X, W, Ld, Ll, Out);
}

// Round 2
// 595.577 us; speedup vs baseline: 1.3134x; 1.3134x over previous
//
#include <hip/hip_runtime.h>
#include <hip/hip_bf16.h>
#include <math.h>

// Problem constants
#define B_SZ   1024   // batch
#define D_SZ   512    // in_features
#define KC_SZ  256    // out_features (classes)
#define NLOW   130816 // 512*511/2

// Tile config
#define BM 128
#define BN 128
#define BK 32
#define LDA 40        // padded LDS stride (bf16 elems)

typedef __attribute__((ext_vector_type(4))) float  f32x4;
typedef __attribute__((ext_vector_type(8))) __bf16 bf16x8;

// Flattened triangular step schedule: 40 steps = 16+12+8+4 over 4 col-tiles.
__device__ __forceinline__ void step_map(int s, int& ct, int& k0) {
    if (s < 16)      { ct = 0; k0 = s * BK; }
    else if (s < 28) { ct = 1; k0 = 128 + (s - 16) * BK; }
    else if (s < 36) { ct = 2; k0 = 256 + (s - 28) * BK; }
    else             { ct = 3; k0 = 384 + (s - 36) * BK; }
}

// out[b,k] = || (x_b - w_k)^T L_k ||_2  with L_k lower-triangular.
// GEMM D[b][e] = sum_d V[b][d] * L[d][e] (V = x - w), fused row-norm.
__global__ __launch_bounds__(256, 2)
void gml2_kernel(const float* __restrict__ X,
                 const float* __restrict__ W,
                 const float* __restrict__ Ldiag,
                 const float* __restrict__ Llow,
                 float* __restrict__ Out) {
    __shared__ __bf16 As[BM * LDA];
    __shared__ __bf16 Bs[BN * LDA];
    __shared__ float  Ws[D_SZ];
    __shared__ float  osum[2][BM];

    const int tid = threadIdx.x;
    const int bx  = blockIdx.x;
    // XCD swizzle: dispatcher round-robins consecutive blocks across 8 XCDs.
    // Hold xcd = bx&7 constant for all 8 row-tiles of one class -> L_k read
    // once into that XCD's L2 (523 KB < 4 MB) instead of 8 fetch streams.
    const int xcd = bx & 7;
    const int g   = bx >> 3;
    const int kc  = xcd * 32 + (g >> 3);  // class
    const int mt  = g & 7;                // row tile

    const int lane = tid & 63;
    const int wave = tid >> 6;
    const int wm   = (wave & 1) * 64;
    const int wn   = (wave >> 1) * 64;
    const int c    = lane & 15;
    const int q    = lane >> 4;

    // A staging map: thread -> (row m, k-half)
    const int am  = tid >> 1;
    const int akh = (tid & 1) << 4;
    const float* xrow = X + (size_t)(mt * BM + am) * D_SZ;
    const float* wrow = W + (size_t)kc * D_SZ;

    // B staging map: thread -> (col e, d-half)
    const int be = tid & 127;
    const int bd = (tid >> 7) << 4;
    const float* lowbase  = Llow  + (size_t)kc * NLOW;
    const float* diagbase = Ldiag + (size_t)kc * D_SZ;

    // Stage W (one row, 2 KB) into LDS once; removes W from the hot loop.
    if (tid < 128) ((f32x4*)Ws)[tid] = ((const f32x4*)wrow)[tid];

    float rsum[16];
    #pragma unroll
    for (int i = 0; i < 16; ++i) rsum[i] = 0.f;

    f32x4 acc[4][4];
    #pragma unroll
    for (int mi = 0; mi < 4; ++mi)
        #pragma unroll
        for (int ni = 0; ni < 4; ++ni)
            acc[mi][ni] = (f32x4){0.f, 0.f, 0.f, 0.f};

    // ---- register prefetch buffers (software pipeline) ----
    f32x4 xr[4];    // X chunk for step s
    float bb[16];   // gathered L column-slice for step s

    auto prefetch = [&](int s) {
        int pct, pk0; step_map(s, pct, pk0);
        const int pe0 = pct * BN;
        const float* xp = xrow + pk0 + akh;
        #pragma unroll
        for (int i = 0; i < 4; ++i) xr[i] = ((const f32x4*)xp)[i];
        const int e  = pe0 + be;
        const int d0 = pk0 + bd;
        int tri = (d0 * (d0 - 1)) >> 1;
        if (pk0 >= pe0 + BN) {
            // tile fully below diagonal: unconditional gather
            #pragma unroll
            for (int j = 0; j < 16; ++j) { bb[j] = lowbase[tri + e]; tri += d0 + j; }
        } else {
            #pragma unroll
            for (int j = 0; j < 16; ++j) {
                const int d = d0 + j;
                float val = 0.f;
                if (d > e)       val = lowbase[tri + e];
                else if (d == e) { float dq = diagbase[d]; val = dq * dq; }
                bb[j] = val;
                tri += d;
            }
        }
    };

    prefetch(0);
    __syncthreads();   // Ws visible

    int cur_ct = 0;
    for (int s = 0; s < 40; ++s) {
        int ct, k0; step_map(s, ct, k0);
        if (ct != cur_ct) {
            // col-tile done: fold acc^2 into row sums, restart acc
            #pragma unroll
            for (int mi = 0; mi < 4; ++mi)
                #pragma unroll
                for (int ni = 0; ni < 4; ++ni)
                    #pragma unroll
                    for (int r = 0; r < 4; ++r) {
                        float y = acc[mi][ni][r];
                        rsum[mi * 4 + r] += y * y;
                        acc[mi][ni][r] = 0.f;
                    }
            cur_ct = ct;
        }

        // ---- convert prefetched regs -> bf16 (VALU only; vmcnt waits land here,
        //      after the previous step's MFMAs) ----
        bf16x8 ap0, ap1;
        {
            const f32x4* wsp = (const f32x4*)&Ws[k0 + akh];
            #pragma unroll
            for (int i = 0; i < 4; ++i) {
                f32x4 wv = wsp[i];
                #pragma unroll
                for (int l = 0; l < 4; ++l) {
                    float v = xr[i][l] - wv[l];
                    int idx = i * 4 + l;
                    if (idx < 8) ap0[idx] = (__bf16)v;
                    else         ap1[idx - 8] = (__bf16)v;
                }
            }
        }
        bf16x8 bp0, bp1;
        #pragma unroll
        for (int j = 0; j < 8; ++j) { bp0[j] = (__bf16)bb[j]; bp1[j] = (__bf16)bb[j + 8]; }

        __syncthreads();   // WAR: all waves done reading previous tiles
        *(bf16x8*)&As[am * LDA + akh]     = ap0;
        *(bf16x8*)&As[am * LDA + akh + 8] = ap1;
        *(bf16x8*)&Bs[be * LDA + bd]      = bp0;
        *(bf16x8*)&Bs[be * LDA + bd + 8]  = bp1;

        // issue next step's global loads NOW; they stay in flight across the
        // barrier + ds_read + 16 MFMAs below (register-destined loads are not
        // drained by s_barrier)
        if (s + 1 < 40) prefetch(s + 1);

        __syncthreads();   // RAW: tiles visible
        bf16x8 af[4], bfr[4];
        #pragma unroll
        for (int mi = 0; mi < 4; ++mi)
            af[mi] = *(const bf16x8*)&As[(wm + mi * 16 + c) * LDA + q * 8];
        #pragma unroll
        for (int ni = 0; ni < 4; ++ni)
            bfr[ni] = *(const bf16x8*)&Bs[(wn + ni * 16 + c) * LDA + q * 8];
        #pragma unroll
        for (int mi = 0; mi < 4; ++mi)
            #pragma unroll
            for (int ni = 0; ni < 4; ++ni)
                acc[mi][ni] = __builtin_amdgcn_mfma_f32_16x16x32_bf16(
                    af[mi], bfr[ni], acc[mi][ni], 0, 0, 0);
    }

    // fold last col-tile
    #pragma unroll
    for (int mi = 0; mi < 4; ++mi)
        #pragma unroll
        for (int ni = 0; ni < 4; ++ni)
            #pragma unroll
            for (int r = 0; r < 4; ++r) {
                float y = acc[mi][ni][r];
                rsum[mi * 4 + r] += y * y;
            }

    // reduce across the 16 col-lanes of each quad (cols within this wave's 64)
    #pragma unroll
    for (int i = 0; i < 16; ++i) {
        float s = rsum[i];
        s += __shfl_xor(s, 1, 64);
        s += __shfl_xor(s, 2, 64);
        s += __shfl_xor(s, 4, 64);
        s += __shfl_xor(s, 8, 64);
        rsum[i] = s;
    }
    const int wnIdx = wave >> 1;
    if (c == 0) {
        #pragma unroll
        for (int mi = 0; mi < 4; ++mi)
            #pragma unroll
            for (int r = 0; r < 4; ++r)
                osum[wnIdx][wm + mi * 16 + q * 4 + r] = rsum[mi * 4 + r];
    }
    __syncthreads();
    if (tid < BM) {
        float s = osum[0][tid] + osum[1][tid];
        Out[(size_t)(mt * BM + tid) * KC_SZ + kc] = sqrtf(s);
    }
}

extern "C" void kernel_launch(void* const* d_in, const int* in_sizes, int n_in,
                              void* d_out, int out_size, void* d_ws, size_t ws_size,
                              hipStream_t stream) {
    const float* X  = (const float*)d_in[0];  // [1024, 512]
    const float* W  = (const float*)d_in[1];  // [256, 1, 512]
    const float* Ld = (const float*)d_in[2];  // [256, 512]
    const float* Ll = (const float*)d_in[3];  // [256, 130816]
    float* Out = (float*)d_out;               // [1024, 256]

    dim3 grid(KC_SZ * (B_SZ / BM));           // 2048 blocks
    dim3 block(256);
    gml2_kernel<<<grid, block, 0, stream>>>(X, W, Ld, Ll, Out);
}

// Round 3
// 449.165 us; speedup vs baseline: 1.7415x; 1.3260x over previous
//
#include <hip/hip_runtime.h>
#include <hip/hip_bf16.h>
#include <math.h>

// Problem constants
#define B_SZ   1024
#define D_SZ   512
#define KC_SZ  256
#define NLOW   130816          // 512*511/2
#define BMAT_STRIDE (D_SZ * D_SZ)   // per-class bf16 elems in workspace

// Main-kernel tile config
#define BM 128
#define BN 128
#define LDA 72                 // As stride in bf16 (144 B): bank-minimum for reads AND writes

typedef __attribute__((ext_vector_type(4))) float  f32x4;
typedef __attribute__((ext_vector_type(8))) __bf16 bf16x8;

__device__ __forceinline__ void load_lds_16B(const __bf16* g, __bf16* l) {
    __builtin_amdgcn_global_load_lds(
        (const __attribute__((address_space(1))) unsigned int*)g,
        (__attribute__((address_space(3))) unsigned int*)l, 16, 0, 0);
}

// ---------------------------------------------------------------------------
// K1: materialize Bmat[k][e][d] = L_k[d][e] in bf16 (only region d >= 128*floor(e/128)).
// 64x64 transpose tiles through LDS. Three tile types: zero (d0+64<=e0),
// diagonal (d0==e0), strict-lower copy (d0>=e0+64).
// ---------------------------------------------------------------------------
__global__ __launch_bounds__(256)
void prep_kernel(const float* __restrict__ Ldiag,
                 const float* __restrict__ Llow,
                 __hip_bfloat16* __restrict__ Bmat) {
    __shared__ float Ls[64][65];   // +1 pad: odd stride -> conflict-free transpose reads

    const int bid = blockIdx.x;
    const int kc = bid >> 6;
    const int et = (bid >> 3) & 7;   // e 64-tile
    const int dt = bid & 7;          // d 64-tile
    const int dmin = (et >> 1) << 1; // d >= 128*floor(e0/128)
    if (dt < dmin) return;

    const int e0 = et << 6, d0 = dt << 6;
    const int tid = threadIdx.x;
    const int r  = tid >> 2;          // 0..63
    const int cq = (tid & 3) << 4;    // col chunk 0/16/32/48

    __bf16* out = (__bf16*)Bmat + (size_t)kc * BMAT_STRIDE;

    if (d0 + 64 <= e0) {
        // zero tile: e > d everywhere
        bf16x8 z;
        #pragma unroll
        for (int i = 0; i < 8; ++i) z[i] = (__bf16)0.f;
        __bf16* dst = out + (size_t)(e0 + r) * D_SZ + d0 + cq;
        *(bf16x8*)dst = z;
        *(bf16x8*)(dst + 8) = z;
        return;
    }

    const float* lowb = Llow + (size_t)kc * NLOW;
    const int d   = d0 + r;
    const int tri = (d * (d - 1)) >> 1;

    if (d0 >= e0 + 64) {
        // strictly lower: d > e for every element -> plain copy
        #pragma unroll
        for (int j = 0; j < 16; ++j) Ls[r][cq + j] = lowb[tri + e0 + cq + j];
    } else {
        // diagonal tile (d0 == e0): per-element classify (guards the tri(511)+511 OOB)
        const float* diagb = Ldiag + (size_t)kc * D_SZ;
        #pragma unroll
        for (int j = 0; j < 16; ++j) {
            const int e = e0 + cq + j;
            float v = 0.f;
            if (e < d)       v = lowb[tri + e];
            else if (e == d) { float q = diagb[d]; v = q * q; }
            Ls[r][cq + j] = v;
        }
    }
    __syncthreads();
    // transposed write: row e = e0 + r, cols d0+cq..+15
    float tv[16];
    #pragma unroll
    for (int j = 0; j < 16; ++j) tv[j] = Ls[cq + j][r];
    bf16x8 p0, p1;
    #pragma unroll
    for (int j = 0; j < 8; ++j) { p0[j] = (__bf16)tv[j]; p1[j] = (__bf16)tv[j + 8]; }
    __bf16* dst = out + (size_t)(e0 + r) * D_SZ + d0 + cq;
    *(bf16x8*)dst = p0;
    *(bf16x8*)(dst + 8) = p1;
}

// ---------------------------------------------------------------------------
// K2: main GEMM. D[b][e] = sum_d (x[b][d]-w[d]) * Bmat[e][d], fused row-norm.
// BK=64 per barrier-pair (two 32-wide B half-tiles via global_load_lds).
// Triangular step schedule: 8+6+4+2 = 20 steps.
// ---------------------------------------------------------------------------
__device__ __forceinline__ void step_map64(int s, int& ct, int& k0) {
    if (s < 8)       { ct = 0; k0 = s << 6; }
    else if (s < 14) { ct = 1; k0 = 128 + ((s - 8) << 6); }
    else if (s < 18) { ct = 2; k0 = 256 + ((s - 14) << 6); }
    else             { ct = 3; k0 = 384 + ((s - 18) << 6); }
}

__global__ __launch_bounds__(256, 3)
void gml2_main(const float* __restrict__ X,
               const float* __restrict__ W,
               const __hip_bfloat16* __restrict__ Bmat,
               float* __restrict__ Out) {
    __shared__ __bf16 As[BM * LDA];        // 18432 B
    __shared__ __bf16 Bs[2][BN * 32];      // 2 x 8192 B, unpadded (global_load_lds layout)
    __shared__ float  Ws[D_SZ];            // 2048 B
    __shared__ float  osum[2][BM];         // 1024 B

    const int tid = threadIdx.x;
    const int bx  = blockIdx.x;
    // XCD swizzle: all 8 row-tiles of a class on one XCD -> Bmat L2-resident
    const int xcd = bx & 7;
    const int g   = bx >> 3;
    const int kc  = xcd * 32 + (g >> 3);
    const int mt  = g & 7;

    const int lane = tid & 63;
    const int wave = tid >> 6;
    const int wm   = (wave & 1) * 64;
    const int wn   = (wave >> 1) * 64;
    const int c    = lane & 15;
    const int q    = lane >> 4;

    // A staging map: row am, k-half (0/32) of the 64-wide slice
    const int am  = tid >> 1;
    const int akh = (tid & 1) << 5;
    const float* xrow = X + (size_t)(mt * BM + am) * D_SZ;
    const float* wrow = W + (size_t)kc * D_SZ;
    const __bf16* bmat_k = (const __bf16*)Bmat + (size_t)kc * BMAT_STRIDE;

    // B staging map: 4 x 16 B per thread (h=0..1, i=0..1)
    const int bcol = (lane & 3) << 3;      // d sub-offset (bf16)
    const int brow = (lane >> 2);          // within 16-row group

    if (tid < 128) ((f32x4*)Ws)[tid] = ((const f32x4*)wrow)[tid];

    float rsum[16];
    #pragma unroll
    for (int i = 0; i < 16; ++i) rsum[i] = 0.f;
    f32x4 acc[4][4];
    #pragma unroll
    for (int mi = 0; mi < 4; ++mi)
        #pragma unroll
        for (int ni = 0; ni < 4; ++ni)
            acc[mi][ni] = (f32x4){0.f, 0.f, 0.f, 0.f};

    // X register prefetch for step 0
    f32x4 xr[8];
    {
        const float* xp = xrow + akh;
        #pragma unroll
        for (int i = 0; i < 8; ++i) xr[i] = ((const f32x4*)xp)[i];
    }

    __syncthreads();   // Ws visible

    int cur_ct = 0;
    for (int s = 0; s < 20; ++s) {
        int ct, k0; step_map64(s, ct, k0);
        if (ct != cur_ct) {
            #pragma unroll
            for (int mi = 0; mi < 4; ++mi)
                #pragma unroll
                for (int ni = 0; ni < 4; ++ni)
                    #pragma unroll
                    for (int r = 0; r < 4; ++r) {
                        float y = acc[mi][ni][r];
                        rsum[mi * 4 + r] += y * y;
                        acc[mi][ni][r] = 0.f;
                    }
            cur_ct = ct;
        }
        const int e0 = ct << 7;

        // ---- pack A: V = x - w -> bf16 (VALU; xr's vmcnt wait lands here) ----
        bf16x8 ap[4];
        {
            const f32x4* wsp = (const f32x4*)&Ws[k0 + akh];
            #pragma unroll
            for (int i2 = 0; i2 < 4; ++i2) {
                f32x4 a0 = xr[2 * i2], a1 = xr[2 * i2 + 1];
                f32x4 w0 = wsp[2 * i2], w1 = wsp[2 * i2 + 1];
                #pragma unroll
                for (int l = 0; l < 4; ++l) {
                    ap[i2][l]     = (__bf16)(a0[l] - w0[l]);
                    ap[i2][l + 4] = (__bf16)(a1[l] - w1[l]);
                }
            }
        }

        __syncthreads();   // WAR: previous tiles consumed

        // ---- B: direct global->LDS DMA, two 8 KB half-tiles ----
        #pragma unroll
        for (int h = 0; h < 2; ++h)
            #pragma unroll
            for (int i = 0; i < 2; ++i) {
                const int r = ((i << 2) + wave) * 16 + brow;  // e row in tile
                load_lds_16B(bmat_k + (size_t)(e0 + r) * D_SZ + k0 + (h << 5) + bcol,
                             &Bs[h][r * 32 + bcol]);
            }

        // ---- A: LDS writes ----
        #pragma unroll
        for (int j = 0; j < 4; ++j)
            *(bf16x8*)&As[am * LDA + akh + 8 * j] = ap[j];

        // ---- prefetch next step's X (overlaps with the barrier drain) ----
        if (s + 1 < 20) {
            int nct, nk0; step_map64(s + 1, nct, nk0);
            const float* xp = xrow + nk0 + akh;
            #pragma unroll
            for (int i = 0; i < 8; ++i) xr[i] = ((const f32x4*)xp)[i];
        }

        __syncthreads();   // RAW: tiles visible (drains vmcnt incl. B DMA)

        // ---- fragments + 32 MFMA ----
        bf16x8 af[4][2], bfr[4][2];
        #pragma unroll
        for (int mi = 0; mi < 4; ++mi)
            #pragma unroll
            for (int h = 0; h < 2; ++h)
                af[mi][h] = *(const bf16x8*)&As[(wm + mi * 16 + c) * LDA + (h << 5) + q * 8];
        #pragma unroll
        for (int ni = 0; ni < 4; ++ni)
            #pragma unroll
            for (int h = 0; h < 2; ++h)
                bfr[ni][h] = *(const bf16x8*)&Bs[h][(wn + ni * 16 + c) * 32 + q * 8];
        #pragma unroll
        for (int mi = 0; mi < 4; ++mi)
            #pragma unroll
            for (int ni = 0; ni < 4; ++ni)
                #pragma unroll
                for (int h = 0; h < 2; ++h)
                    acc[mi][ni] = __builtin_amdgcn_mfma_f32_16x16x32_bf16(
                        af[mi][h], bfr[ni][h], acc[mi][ni], 0, 0, 0);
    }

    // fold last col-tile
    #pragma unroll
    for (int mi = 0; mi < 4; ++mi)
        #pragma unroll
        for (int ni = 0; ni < 4; ++ni)
            #pragma unroll
            for (int r = 0; r < 4; ++r) {
                float y = acc[mi][ni][r];
                rsum[mi * 4 + r] += y * y;
            }

    // reduce the 16 e-lanes of each quad
    #pragma unroll
    for (int i = 0; i < 16; ++i) {
        float s = rsum[i];
        s += __shfl_xor(s, 1, 64);
        s += __shfl_xor(s, 2, 64);
        s += __shfl_xor(s, 4, 64);
        s += __shfl_xor(s, 8, 64);
        rsum[i] = s;
    }
    const int wnIdx = wave >> 1;
    if (c == 0) {
        #pragma unroll
        for (int mi = 0; mi < 4; ++mi)
            #pragma unroll
            for (int r = 0; r < 4; ++r)
                osum[wnIdx][wm + mi * 16 + q * 4 + r] = rsum[mi * 4 + r];
    }
    __syncthreads();
    if (tid < BM) {
        float s = osum[0][tid] + osum[1][tid];
        Out[(size_t)(mt * BM + tid) * KC_SZ + kc] = sqrtf(s);
    }
}

// ---------------------------------------------------------------------------
// Fallback (round-2 kernel, proven): used only if ws_size < 128 MiB.
// ---------------------------------------------------------------------------
#define FLDA 40
__device__ __forceinline__ void fstep_map(int s, int& ct, int& k0) {
    if (s < 16)      { ct = 0; k0 = s * 32; }
    else if (s < 28) { ct = 1; k0 = 128 + (s - 16) * 32; }
    else if (s < 36) { ct = 2; k0 = 256 + (s - 28) * 32; }
    else             { ct = 3; k0 = 384 + (s - 36) * 32; }
}
__global__ __launch_bounds__(256, 2)
void gml2_fallback(const float* __restrict__ X, const float* __restrict__ W,
                   const float* __restrict__ Ldiag, const float* __restrict__ Llow,
                   float* __restrict__ Out) {
    __shared__ __bf16 As[BM * FLDA];
    __shared__ __bf16 Bs[BN * FLDA];
    __shared__ float  Ws[D_SZ];
    __shared__ float  osum[2][BM];
    const int tid = threadIdx.x;
    const int bx  = blockIdx.x;
    const int xcd = bx & 7;
    const int g   = bx >> 3;
    const int kc  = xcd * 32 + (g >> 3);
    const int mt  = g & 7;
    const int lane = tid & 63, wave = tid >> 6;
    const int wm = (wave & 1) * 64, wn = (wave >> 1) * 64;
    const int c = lane & 15, q = lane >> 4;
    const int am = tid >> 1, akh = (tid & 1) << 4;
    const float* xrow = X + (size_t)(mt * BM + am) * D_SZ;
    const float* wrow = W + (size_t)kc * D_SZ;
    const int be = tid & 127, bd = (tid >> 7) << 4;
    const float* lowbase  = Llow  + (size_t)kc * NLOW;
    const float* diagbase = Ldiag + (size_t)kc * D_SZ;
    if (tid < 128) ((f32x4*)Ws)[tid] = ((const f32x4*)wrow)[tid];
    float rsum[16];
    #pragma unroll
    for (int i = 0; i < 16; ++i) rsum[i] = 0.f;
    f32x4 acc[4][4];
    #pragma unroll
    for (int mi = 0; mi < 4; ++mi)
        #pragma unroll
        for (int ni = 0; ni < 4; ++ni) acc[mi][ni] = (f32x4){0.f, 0.f, 0.f, 0.f};
    f32x4 xr[4];
    float bb[16];
    auto prefetch = [&](int s) {
        int pct, pk0; fstep_map(s, pct, pk0);
        const int pe0 = pct * BN;
        const float* xp = xrow + pk0 + akh;
        #pragma unroll
        for (int i = 0; i < 4; ++i) xr[i] = ((const f32x4*)xp)[i];
        const int e = pe0 + be, d0 = pk0 + bd;
        int tri = (d0 * (d0 - 1)) >> 1;
        if (pk0 >= pe0 + BN) {
            #pragma unroll
            for (int j = 0; j < 16; ++j) { bb[j] = lowbase[tri + e]; tri += d0 + j; }
        } else {
            #pragma unroll
            for (int j = 0; j < 16; ++j) {
                const int d = d0 + j;
                float val = 0.f;
                if (d > e)       val = lowbase[tri + e];
                else if (d == e) { float dq = diagbase[d]; val = dq * dq; }
                bb[j] = val; tri += d;
            }
        }
    };
    prefetch(0);
    __syncthreads();
    int cur_ct = 0;
    for (int s = 0; s < 40; ++s) {
        int ct, k0; fstep_map(s, ct, k0);
        if (ct != cur_ct) {
            #pragma unroll
            for (int mi = 0; mi < 4; ++mi)
                #pragma unroll
                for (int ni = 0; ni < 4; ++ni)
                    #pragma unroll
                    for (int r = 0; r < 4; ++r) {
                        float y = acc[mi][ni][r];
                        rsum[mi * 4 + r] += y * y;
                        acc[mi][ni][r] = 0.f;
                    }
            cur_ct = ct;
        }
        bf16x8 ap0, ap1;
        {
            const f32x4* wsp = (const f32x4*)&Ws[k0 + akh];
            #pragma unroll
            for (int i = 0; i < 4; ++i) {
                f32x4 wv = wsp[i];
                #pragma unroll
                for (int l = 0; l < 4; ++l) {
                    float v = xr[i][l] - wv[l];
                    int idx = i * 4 + l;
                    if (idx < 8) ap0[idx] = (__bf16)v;
                    else         ap1[idx - 8] = (__bf16)v;
                }
            }
        }
        bf16x8 bp0, bp1;
        #pragma unroll
        for (int j = 0; j < 8; ++j) { bp0[j] = (__bf16)bb[j]; bp1[j] = (__bf16)bb[j + 8]; }
        __syncthreads();
        *(bf16x8*)&As[am * FLDA + akh]     = ap0;
        *(bf16x8*)&As[am * FLDA + akh + 8] = ap1;
        *(bf16x8*)&Bs[be * FLDA + bd]      = bp0;
        *(bf16x8*)&Bs[be * FLDA + bd + 8]  = bp1;
        if (s + 1 < 40) prefetch(s + 1);
        __syncthreads();
        bf16x8 af[4], bfr[4];
        #pragma unroll
        for (int mi = 0; mi < 4; ++mi)
            af[mi] = *(const bf16x8*)&As[(wm + mi * 16 + c) * FLDA + q * 8];
        #pragma unroll
        for (int ni = 0; ni < 4; ++ni)
            bfr[ni] = *(const bf16x8*)&Bs[(wn + ni * 16 + c) * FLDA + q * 8];
        #pragma unroll
        for (int mi = 0; mi < 4; ++mi)
            #pragma unroll
            for (int ni = 0; ni < 4; ++ni)
                acc[mi][ni] = __builtin_amdgcn_mfma_f32_16x16x32_bf16(
                    af[mi], bfr[ni], acc[mi][ni], 0, 0, 0);
    }
    #pragma unroll
    for (int mi = 0; mi < 4; ++mi)
        #pragma unroll
        for (int ni = 0; ni < 4; ++ni)
            #pragma unroll
            for (int r = 0; r < 4; ++r) {
                float y = acc[mi][ni][r];
                rsum[mi * 4 + r] += y * y;
            }
    #pragma unroll
    for (int i = 0; i < 16; ++i) {
        float s = rsum[i];
        s += __shfl_xor(s, 1, 64);
        s += __shfl_xor(s, 2, 64);
        s += __shfl_xor(s, 4, 64);
        s += __shfl_xor(s, 8, 64);
        rsum[i] = s;
    }
    const int wnIdx = wave >> 1;
    if (c == 0) {
        #pragma unroll
        for (int mi = 0; mi < 4; ++mi)
            #pragma unroll
            for (int r = 0; r < 4; ++r)
                osum[wnIdx][wm + mi * 16 + q * 4 + r] = rsum[mi * 4 + r];
    }
    __syncthreads();
    if (tid < BM) {
        float s = osum[0][tid] + osum[1][tid];
        Out[(size_t)(mt * BM + tid) * KC_SZ + kc] = sqrtf(s);
    }
}

extern "C" void kernel_launch(void* const* d_in, const int* in_sizes, int n_in,
                              void* d_out, int out_size, void* d_ws, size_t ws_size,
                              hipStream_t stream) {
    const float* X  = (const float*)d_in[0];
    const float* W  = (const float*)d_in[1];
    const float* Ld = (const float*)d_in[2];
    const float* Ll = (const float*)d_in[3];
    float* Out = (float*)d_out;

    const size_t need = (size_t)KC_SZ * BMAT_STRIDE * sizeof(__hip_bfloat16); // 128 MiB
    if (ws_size >= need) {
        __hip_bfloat16* Bmat = (__hip_bfloat16*)d_ws;
        prep_kernel<<<dim3(KC_SZ * 64), dim3(256), 0, stream>>>(Ld, Ll, Bmat);
        gml2_main<<<dim3(KC_SZ * (B_SZ / BM)), dim3(256), 0, stream>>>(X, W, Bmat, Out);
    } else {
        gml2_fallback<<<dim3(KC_SZ * (B_SZ / BM)), dim3(256), 0, stream>>>(X, W, Ld, Ll, Out);
    }
}

// Round 4
// 439.313 us; speedup vs baseline: 1.7805x; 1.0224x over previous
//
#include <hip/hip_runtime.h>
#include <hip/hip_bf16.h>
#include <math.h>

// Problem constants
#define B_SZ   1024
#define D_SZ   512
#define KC_SZ  256
#define NLOW   130816            // 512*511/2

// Compact pre-transformed B storage: per class, 20 K-step pages of 16 KB,
// each page already in the main kernel's LDS image layout [h][q][e][8]:
//   elem offset = h*4096 + q*1024 + e*8 + (d&7),  h=(d_local>>5), q=(d_local>>3)&3
#define STEP_ELEMS  8192         // bf16 per step page (16 KB)
#define NSTEPS      20           // 8+6+4+2 triangular K-steps
#define CLASS_ELEMS (NSTEPS * STEP_ELEMS)   // 163840 bf16 = 320 KB/class

// Main-kernel tile config
#define BM 128
#define BN 128
#define LDA 72                   // As stride (bf16): 2-way bank pattern = free

typedef __attribute__((ext_vector_type(4))) float  f32x4;
typedef __attribute__((ext_vector_type(8))) __bf16 bf16x8;

__device__ __forceinline__ void load_lds_16B(const __bf16* g, __bf16* l) {
    __builtin_amdgcn_global_load_lds(
        (const __attribute__((address_space(1))) unsigned int*)g,
        (__attribute__((address_space(3))) unsigned int*)l, 16, 0, 0);
}

// steps before col-tile ct: 0,8,14,18  ==  ct*(9-ct)
__device__ __forceinline__ int sbase_of(int ct) { return ct * (9 - ct); }

__device__ __forceinline__ void step_map64(int s, int& ct, int& k0) {
    if (s < 8)       { ct = 0; k0 = s << 6; }
    else if (s < 14) { ct = 1; k0 = 128 + ((s - 8) << 6); }
    else if (s < 18) { ct = 2; k0 = 256 + ((s - 14) << 6); }
    else             { ct = 3; k0 = 384 + ((s - 18) << 6); }
}

// ---------------------------------------------------------------------------
// K1: build the pre-swizzled compact Bmat pages.
// One block per (class, 64x64 (e,d) tile) with tiles restricted to the
// d >= 128*floor(e/128) region (the only region main reads).
// ---------------------------------------------------------------------------
__global__ __launch_bounds__(256)
void prep_kernel(const float* __restrict__ Ldiag,
                 const float* __restrict__ Llow,
                 __hip_bfloat16* __restrict__ Bmat) {
    __shared__ float Ls[64][65];   // [d_in_tile][e_in_tile], odd stride

    const int bid = blockIdx.x;
    const int kc  = bid >> 6;
    const int et  = (bid >> 3) & 7;   // e 64-tile
    const int dt  = bid & 7;          // d 64-tile
    const int ct  = et >> 1;          // col-supertile
    const int dmin = ct << 1;
    if (dt < dmin) return;            // region main never reads

    const int s  = sbase_of(ct) + (dt - dmin);   // global K-step page id
    const int e0 = et << 6, d0 = dt << 6;
    const int tid = threadIdx.x;

    __bf16* page = (__bf16*)Bmat + (size_t)kc * CLASS_ELEMS + (size_t)s * STEP_ELEMS;

    // output mapping: thread -> d-chunk qp (8 chunks of 8), e-pair ep
    // writes 32 contiguous bytes: [e=2ep][8] and [e=2ep+1][8]
    const int qp = tid >> 5;          // 0..7
    const int ep = tid & 31;          // 0..31
    const int elocal = ((et & 1) << 6) + (ep << 1);
    __bf16* dst = page + ((qp >> 2) << 12) + ((qp & 3) << 10) + elocal * 8;

    if (d0 + 64 <= e0) {
        // zero tile (inside diagonal supertile, e > d everywhere)
        bf16x8 z;
        #pragma unroll
        for (int i = 0; i < 8; ++i) z[i] = (__bf16)0.f;
        *(bf16x8*)dst = z;
        *(bf16x8*)(dst + 8) = z;
        return;
    }

    // stage tile into LDS, d-major, coalesced reads of the packed triangle
    const int r  = tid >> 2;          // d row 0..63
    const int cq = (tid & 3) << 4;    // e col chunk
    const float* lowb = Llow + (size_t)kc * NLOW;
    const int d   = d0 + r;
    const int tri = (d * (d - 1)) >> 1;

    if (d0 >= e0 + 64) {
        // strictly lower: d > e everywhere -> plain copy
        #pragma unroll
        for (int j = 0; j < 16; ++j) Ls[r][cq + j] = lowb[tri + e0 + cq + j];
    } else {
        // diagonal tile (d0 == e0)
        const float* diagb = Ldiag + (size_t)kc * D_SZ;
        #pragma unroll
        for (int j = 0; j < 16; ++j) {
            const int e = e0 + cq + j;
            float v = 0.f;
            if (e < d)       v = lowb[tri + e];
            else if (e == d) { float qd = diagb[d]; v = qd * qd; }
            Ls[r][cq + j] = v;
        }
    }
    __syncthreads();
    // transpose out: d rows qp*8..+7, e cols 2ep, 2ep+1
    bf16x8 p0, p1;
    #pragma unroll
    for (int j = 0; j < 8; ++j) {
        float t0 = Ls[qp * 8 + j][ep * 2];
        float t1 = Ls[qp * 8 + j][ep * 2 + 1];
        p0[j] = (__bf16)t0;
        p1[j] = (__bf16)t1;
    }
    *(bf16x8*)dst = p0;
    *(bf16x8*)(dst + 8) = p1;
}

// ---------------------------------------------------------------------------
// K2: main GEMM. D[b][e] = sum_d (x[b][d]-w[d]) * L[d][e], fused row-norm.
// B staging = 4 contiguous 1-KB DMAs per wave from the pre-swizzled page.
// ---------------------------------------------------------------------------
__global__ __launch_bounds__(256, 3)
void gml2_main(const float* __restrict__ X,
               const float* __restrict__ W,
               const __hip_bfloat16* __restrict__ Bmat,
               float* __restrict__ Out) {
    __shared__ __bf16 As[BM * LDA];    // 18432 B
    __shared__ __bf16 Bs[STEP_ELEMS];  // 16384 B, [h][q][e][8] image
    __shared__ float  Ws[D_SZ];        // 2048 B
    __shared__ float  osum[2][BM];     // 1024 B

    const int tid = threadIdx.x;
    const int bx  = blockIdx.x;
    // XCD swizzle: all 8 row-tiles of a class on one XCD -> pages L2-resident
    const int xcd = bx & 7;
    const int g   = bx >> 3;
    const int kc  = xcd * 32 + (g >> 3);
    const int mt  = g & 7;

    const int lane = tid & 63;
    const int wave = tid >> 6;
    const int wm   = (wave & 1) * 64;
    const int wn   = (wave >> 1) * 64;
    const int c    = lane & 15;
    const int q    = lane >> 4;

    // A staging map: row am, k-half (0/32)
    const int am  = tid >> 1;
    const int akh = (tid & 1) << 5;
    const float* xrow = X + (size_t)(mt * BM + am) * D_SZ;
    const float* wrow = W + (size_t)kc * D_SZ;
    const __bf16* bmat_k = (const __bf16*)Bmat + (size_t)kc * CLASS_ELEMS;

    if (tid < 128) ((f32x4*)Ws)[tid] = ((const f32x4*)wrow)[tid];

    float rsum[16];
    #pragma unroll
    for (int i = 0; i < 16; ++i) rsum[i] = 0.f;
    f32x4 acc[4][4];
    #pragma unroll
    for (int mi = 0; mi < 4; ++mi)
        #pragma unroll
        for (int ni = 0; ni < 4; ++ni)
            acc[mi][ni] = (f32x4){0.f, 0.f, 0.f, 0.f};

    // X registers for step 0
    f32x4 xr[8];
    {
        const float* xp = xrow + akh;
        #pragma unroll
        for (int i = 0; i < 8; ++i) xr[i] = ((const f32x4*)xp)[i];
    }

    __syncthreads();   // Ws visible

    int cur_ct = 0;
    for (int s = 0; s < NSTEPS; ++s) {
        int ct, k0; step_map64(s, ct, k0);
        if (ct != cur_ct) {
            #pragma unroll
            for (int mi = 0; mi < 4; ++mi)
                #pragma unroll
                for (int ni = 0; ni < 4; ++ni)
                    #pragma unroll
                    for (int r = 0; r < 4; ++r) {
                        float y = acc[mi][ni][r];
                        rsum[mi * 4 + r] += y * y;
                        acc[mi][ni][r] = 0.f;
                    }
            cur_ct = ct;
        }

        // ---- pack A: V = x - w -> bf16 (xr's vmcnt wait lands here) ----
        bf16x8 ap[4];
        {
            const f32x4* wsp = (const f32x4*)&Ws[k0 + akh];
            #pragma unroll
            for (int i2 = 0; i2 < 4; ++i2) {
                f32x4 a0 = xr[2 * i2], a1 = xr[2 * i2 + 1];
                f32x4 w0 = wsp[2 * i2], w1 = wsp[2 * i2 + 1];
                #pragma unroll
                for (int l = 0; l < 4; ++l) {
                    ap[i2][l]     = (__bf16)(a0[l] - w0[l]);
                    ap[i2][l + 4] = (__bf16)(a1[l] - w1[l]);
                }
            }
        }

        __syncthreads();   // WAR: previous tiles consumed

        // ---- B: 4 contiguous 1-KB DMAs per wave from the pre-swizzled page ----
        {
            const __bf16* bstep = bmat_k + (size_t)s * STEP_ELEMS;
            #pragma unroll
            for (int it = 0; it < 4; ++it) {
                const int off = (wave * 4 + it) * 512 + lane * 8;
                load_lds_16B(bstep + off, &Bs[off]);
            }
        }

        // ---- A: LDS writes ----
        #pragma unroll
        for (int j = 0; j < 4; ++j)
            *(bf16x8*)&As[am * LDA + akh + 8 * j] = ap[j];

        __syncthreads();   // RAW: tiles visible (drains the B DMA)

        // ---- prefetch next step's X: drained only at NEXT WAR barrier,
        //      i.e. after the whole MFMA phase below ----
        if (s + 1 < NSTEPS) {
            int nct, nk0; step_map64(s + 1, nct, nk0);
            const float* xp = xrow + nk0 + akh;
            #pragma unroll
            for (int i = 0; i < 8; ++i) xr[i] = ((const f32x4*)xp)[i];
        }

        // ---- fragments + 32 MFMA ----
        bf16x8 af[4][2], bfr[4][2];
        #pragma unroll
        for (int mi = 0; mi < 4; ++mi)
            #pragma unroll
            for (int h = 0; h < 2; ++h)
                af[mi][h] = *(const bf16x8*)&As[(wm + mi * 16 + c) * LDA + (h << 5) + q * 8];
        #pragma unroll
        for (int ni = 0; ni < 4; ++ni)
            #pragma unroll
            for (int h = 0; h < 2; ++h)
                bfr[ni][h] = *(const bf16x8*)&Bs[h * 4096 + q * 1024 + (wn + ni * 16 + c) * 8];
        #pragma unroll
        for (int mi = 0; mi < 4; ++mi)
            #pragma unroll
            for (int ni = 0; ni < 4; ++ni)
                #pragma unroll
                for (int h = 0; h < 2; ++h)
                    acc[mi][ni] = __builtin_amdgcn_mfma_f32_16x16x32_bf16(
                        af[mi][h], bfr[ni][h], acc[mi][ni], 0, 0, 0);
    }

    // fold last col-tile
    #pragma unroll
    for (int mi = 0; mi < 4; ++mi)
        #pragma unroll
        for (int ni = 0; ni < 4; ++ni)
            #pragma unroll
            for (int r = 0; r < 4; ++r) {
                float y = acc[mi][ni][r];
                rsum[mi * 4 + r] += y * y;
            }

    // reduce the 16 e-lanes of each quad
    #pragma unroll
    for (int i = 0; i < 16; ++i) {
        float s = rsum[i];
        s += __shfl_xor(s, 1, 64);
        s += __shfl_xor(s, 2, 64);
        s += __shfl_xor(s, 4, 64);
        s += __shfl_xor(s, 8, 64);
        rsum[i] = s;
    }
    const int wnIdx = wave >> 1;
    if (c == 0) {
        #pragma unroll
        for (int mi = 0; mi < 4; ++mi)
            #pragma unroll
            for (int r = 0; r < 4; ++r)
                osum[wnIdx][wm + mi * 16 + q * 4 + r] = rsum[mi * 4 + r];
    }
    __syncthreads();
    if (tid < BM) {
        float s = osum[0][tid] + osum[1][tid];
        Out[(size_t)(mt * BM + tid) * KC_SZ + kc] = sqrtf(s);
    }
}

// ---------------------------------------------------------------------------
// Fallback (round-2 kernel, proven): used only if ws too small.
// ---------------------------------------------------------------------------
#define FLDA 40
__device__ __forceinline__ void fstep_map(int s, int& ct, int& k0) {
    if (s < 16)      { ct = 0; k0 = s * 32; }
    else if (s < 28) { ct = 1; k0 = 128 + (s - 16) * 32; }
    else if (s < 36) { ct = 2; k0 = 256 + (s - 28) * 32; }
    else             { ct = 3; k0 = 384 + (s - 36) * 32; }
}
__global__ __launch_bounds__(256, 2)
void gml2_fallback(const float* __restrict__ X, const float* __restrict__ W,
                   const float* __restrict__ Ldiag, const float* __restrict__ Llow,
                   float* __restrict__ Out) {
    __shared__ __bf16 As[BM * FLDA];
    __shared__ __bf16 Bs[BN * FLDA];
    __shared__ float  Ws[D_SZ];
    __shared__ float  osum[2][BM];
    const int tid = threadIdx.x;
    const int bx  = blockIdx.x;
    const int xcd = bx & 7;
    const int g   = bx >> 3;
    const int kc  = xcd * 32 + (g >> 3);
    const int mt  = g & 7;
    const int lane = tid & 63, wave = tid >> 6;
    const int wm = (wave & 1) * 64, wn = (wave >> 1) * 64;
    const int c = lane & 15, q = lane >> 4;
    const int am = tid >> 1, akh = (tid & 1) << 4;
    const float* xrow = X + (size_t)(mt * BM + am) * D_SZ;
    const float* wrow = W + (size_t)kc * D_SZ;
    const int be = tid & 127, bd = (tid >> 7) << 4;
    const float* lowbase  = Llow  + (size_t)kc * NLOW;
    const float* diagbase = Ldiag + (size_t)kc * D_SZ;
    if (tid < 128) ((f32x4*)Ws)[tid] = ((const f32x4*)wrow)[tid];
    float rsum[16];
    #pragma unroll
    for (int i = 0; i < 16; ++i) rsum[i] = 0.f;
    f32x4 acc[4][4];
    #pragma unroll
    for (int mi = 0; mi < 4; ++mi)
        #pragma unroll
        for (int ni = 0; ni < 4; ++ni) acc[mi][ni] = (f32x4){0.f, 0.f, 0.f, 0.f};
    f32x4 xr[4];
    float bb[16];
    auto prefetch = [&](int s) {
        int pct, pk0; fstep_map(s, pct, pk0);
        const int pe0 = pct * BN;
        const float* xp = xrow + pk0 + akh;
        #pragma unroll
        for (int i = 0; i < 4; ++i) xr[i] = ((const f32x4*)xp)[i];
        const int e = pe0 + be, d0 = pk0 + bd;
        int tri = (d0 * (d0 - 1)) >> 1;
        if (pk0 >= pe0 + BN) {
            #pragma unroll
            for (int j = 0; j < 16; ++j) { bb[j] = lowbase[tri + e]; tri += d0 + j; }
        } else {
            #pragma unroll
            for (int j = 0; j < 16; ++j) {
                const int d = d0 + j;
                float val = 0.f;
                if (d > e)       val = lowbase[tri + e];
                else if (d == e) { float dq = diagbase[d]; val = dq * dq; }
                bb[j] = val; tri += d;
            }
        }
    };
    prefetch(0);
    __syncthreads();
    int cur_ct = 0;
    for (int s = 0; s < 40; ++s) {
        int ct, k0; fstep_map(s, ct, k0);
        if (ct != cur_ct) {
            #pragma unroll
            for (int mi = 0; mi < 4; ++mi)
                #pragma unroll
                for (int ni = 0; ni < 4; ++ni)
                    #pragma unroll
                    for (int r = 0; r < 4; ++r) {
                        float y = acc[mi][ni][r];
                        rsum[mi * 4 + r] += y * y;
                        acc[mi][ni][r] = 0.f;
                    }
            cur_ct = ct;
        }
        bf16x8 ap0, ap1;
        {
            const f32x4* wsp = (const f32x4*)&Ws[k0 + akh];
            #pragma unroll
            for (int i = 0; i < 4; ++i) {
                f32x4 wv = wsp[i];
                #pragma unroll
                for (int l = 0; l < 4; ++l) {
                    float v = xr[i][l] - wv[l];
                    int idx = i * 4 + l;
                    if (idx < 8) ap0[idx] = (__bf16)v;
                    else         ap1[idx - 8] = (__bf16)v;
                }
            }
        }
        bf16x8 bp0, bp1;
        #pragma unroll
        for (int j = 0; j < 8; ++j) { bp0[j] = (__bf16)bb[j]; bp1[j] = (__bf16)bb[j + 8]; }
        __syncthreads();
        *(bf16x8*)&As[am * FLDA + akh]     = ap0;
        *(bf16x8*)&As[am * FLDA + akh + 8] = ap1;
        *(bf16x8*)&Bs[be * FLDA + bd]      = bp0;
        *(bf16x8*)&Bs[be * FLDA + bd + 8]  = bp1;
        if (s + 1 < 40) prefetch(s + 1);
        __syncthreads();
        bf16x8 af[4], bfr[4];
        #pragma unroll
        for (int mi = 0; mi < 4; ++mi)
            af[mi] = *(const bf16x8*)&As[(wm + mi * 16 + c) * FLDA + q * 8];
        #pragma unroll
        for (int ni = 0; ni < 4; ++ni)
            bfr[ni] = *(const bf16x8*)&Bs[(wn + ni * 16 + c) * FLDA + q * 8];
        #pragma unroll
        for (int mi = 0; mi < 4; ++mi)
            #pragma unroll
            for (int ni = 0; ni < 4; ++ni)
                acc[mi][ni] = __builtin_amdgcn_mfma_f32_16x16x32_bf16(
                    af[mi], bfr[ni], acc[mi][ni], 0, 0, 0);
    }
    #pragma unroll
    for (int mi = 0; mi < 4; ++mi)
        #pragma unroll
        for (int ni = 0; ni < 4; ++ni)
            #pragma unroll
            for (int r = 0; r < 4; ++r) {
                float y = acc[mi][ni][r];
                rsum[mi * 4 + r] += y * y;
            }
    #pragma unroll
    for (int i = 0; i < 16; ++i) {
        float s = rsum[i];
        s += __shfl_xor(s, 1, 64);
        s += __shfl_xor(s, 2, 64);
        s += __shfl_xor(s, 4, 64);
        s += __shfl_xor(s, 8, 64);
        rsum[i] = s;
    }
    const int wnIdx = wave >> 1;
    if (c == 0) {
        #pragma unroll
        for (int mi = 0; mi < 4; ++mi)
            #pragma unroll
            for (int r = 0; r < 4; ++r)
                osum[wnIdx][wm + mi * 16 + q * 4 + r] = rsum[mi * 4 + r];
    }
    __syncthreads();
    if (tid < BM) {
        float s = osum[0][tid] + osum[1][tid];
        Out[(size_t)(mt * BM + tid) * KC_SZ + kc] = sqrtf(s);
    }
}

extern "C" void kernel_launch(void* const* d_in, const int* in_sizes, int n_in,
                              void* d_out, int out_size, void* d_ws, size_t ws_size,
                              hipStream_t stream) {
    const float* X  = (const float*)d_in[0];
    const float* W  = (const float*)d_in[1];
    const float* Ld = (const float*)d_in[2];
    const float* Ll = (const float*)d_in[3];
    float* Out = (float*)d_out;

    const size_t need = (size_t)KC_SZ * CLASS_ELEMS * sizeof(__hip_bfloat16); // 80 MiB
    if (ws_size >= need) {
        __hip_bfloat16* Bmat = (__hip_bfloat16*)d_ws;
        prep_kernel<<<dim3(KC_SZ * 64), dim3(256), 0, stream>>>(Ld, Ll, Bmat);
        gml2_main<<<dim3(KC_SZ * (B_SZ / BM)), dim3(256), 0, stream>>>(X, W, Bmat, Out);
    } else {
        gml2_fallback<<<dim3(KC_SZ * (B_SZ / BM)), dim3(256), 0, stream>>>(X, W, Ld, Ll, Out);
    }
}

// Round 5
// 357.347 us; speedup vs baseline: 2.1890x; 1.2294x over previous
//
#include <hip/hip_runtime.h>
#include <hip/hip_bf16.h>
#include <math.h>

// Problem constants
#define B_SZ   1024
#define D_SZ   512
#define KC_SZ  256
#define NLOW   130816            // 512*511/2

// B pages: per class, 20 K-step pages of 16 KB, stored in per-wave MFMA
// fragment order: line = ((wng*4+ni)*2+h)*64 + lane, lane = q*16+c,
// value[j] = L[d][e], e = wng*64+ni*16+c, d_local = h*32+q*8+j.
#define STEP_ELEMS  8192
#define NSTEPS      20           // 8+6+4+2 triangular K-steps
#define CLASS_ELEMS (NSTEPS * STEP_ELEMS)   // 320 KB/class

// Workspace layout (bytes)
#define OFF_XP     (size_t)(KC_SZ * CLASS_ELEMS * 2)        // 83886080
#define OFF_TPART  (OFF_XP + 64 * STEP_ELEMS * 2)           // +1 MiB
#define OFF_T      (OFF_TPART + (size_t)KC_SZ * 8 * 512 * 4)// +4 MiB
#define WS_NEED    (OFF_T + (size_t)KC_SZ * 512 * 4)        // ~85.5 MiB

typedef __attribute__((ext_vector_type(4))) float  f32x4;
typedef __attribute__((ext_vector_type(8))) __bf16 bf16x8;

// ---------------------------------------------------------------------------
// K1a: X pages, bf16, A-fragment order. 64 pages (mt 0..7 x kchunk 0..7).
// line = ((wmg*4+mi)*2+h)*64 + lane; value[j] = X[mt*128+wmg*64+mi*16+c][kch*64+h*32+q*8+j]
// ---------------------------------------------------------------------------
__global__ __launch_bounds__(256)
void prep_x(const float* __restrict__ X, __hip_bfloat16* __restrict__ Xp) {
    const int pg  = blockIdx.x;          // mt*8 + kch
    const int mt  = pg >> 3, kch = pg & 7;
    __bf16* out = (__bf16*)Xp + (size_t)pg * STEP_ELEMS;
    const int tid = threadIdx.x;
    #pragma unroll
    for (int i = 0; i < 4; ++i) {
        const int line = tid + i * 256;          // 0..1023
        const int wmg = line >> 9, mi = (line >> 7) & 3, h = (line >> 6) & 1;
        const int lane = line & 63, q = lane >> 4, c = lane & 15;
        const int row = mt * 128 + wmg * 64 + mi * 16 + c;
        const float* src = X + (size_t)row * D_SZ + kch * 64 + h * 32 + q * 8;
        f32x4 v0 = ((const f32x4*)src)[0];
        f32x4 v1 = ((const f32x4*)src)[1];
        bf16x8 p;
        #pragma unroll
        for (int j = 0; j < 4; ++j) { p[j] = (__bf16)v0[j]; p[j + 4] = (__bf16)v1[j]; }
        *(bf16x8*)(out + line * 8) = p;
    }
}

// steps before col-tile ct
__device__ __forceinline__ int sbase_of(int ct) { return ct * (9 - ct); }

// ---------------------------------------------------------------------------
// K1b: B pages (fragment order) + t-partials (t_k = w_k^T L_k, fp32).
// One block per (class, 64x64 (e,d) tile), active when dt >= 2*(et>>1).
// ---------------------------------------------------------------------------
__global__ __launch_bounds__(256)
void prep_b(const float* __restrict__ Ldiag,
            const float* __restrict__ Llow,
            const float* __restrict__ W,
            __hip_bfloat16* __restrict__ Bp,
            float* __restrict__ tpart) {
    __shared__ float Ls[64][65];   // [d_local][e_local]
    __shared__ float Wsm[64];
    __shared__ float pt[4][64];

    const int bid = blockIdx.x;
    const int kc  = bid >> 6;
    const int et  = (bid >> 3) & 7;
    const int dt  = bid & 7;
    const int ct  = et >> 1;
    const int dmin = ct << 1;
    if (dt < dmin) return;

    const int s  = sbase_of(ct) + (dt - dmin);
    const int e0 = et << 6, d0 = dt << 6;
    const int tid = threadIdx.x;

    __bf16* page = (__bf16*)Bp + (size_t)kc * CLASS_ELEMS + (size_t)s * STEP_ELEMS;
    float*  tp   = tpart + ((size_t)(kc * 8 + dt)) * 512;

    // output mapping: thread (qp = d-chunk 0..7, ep = e-pair 0..31)
    const int qp = tid >> 5;
    const int ep = tid & 31;
    const int el0 = ((et & 1) << 6) + (ep << 1);      // e_local in page
    const int h = qp >> 2, q = qp & 3;
    // line offset for e_local el: ((el>>6)*4 + ((el>>4)&3))*2 + h) *64 + q*16 + (el&15)
    const int line0 = ((((el0 >> 6) * 4 + ((el0 >> 4) & 3)) * 2 + h) * 64) + q * 16 + (el0 & 15);
    __bf16* dst = page + line0 * 8;    // el0+1 line is dst+8 (contiguous)

    if (d0 + 64 <= e0) {
        // zero tile: e > d everywhere
        bf16x8 z;
        #pragma unroll
        for (int i = 0; i < 8; ++i) z[i] = (__bf16)0.f;
        *(bf16x8*)dst = z;
        *(bf16x8*)(dst + 8) = z;
        if (tid < 64) tp[et * 64 + tid] = 0.f;
        return;
    }

    if (tid < 64) Wsm[tid] = W[(size_t)kc * D_SZ + d0 + tid];

    // stage tile into LDS, d-major
    const int r  = tid >> 2;          // d row 0..63
    const int cq = (tid & 3) << 4;    // e col chunk
    const float* lowb = Llow + (size_t)kc * NLOW;
    const int d   = d0 + r;
    const int tri = (d * (d - 1)) >> 1;

    if (d0 >= e0 + 64) {
        #pragma unroll
        for (int j = 0; j < 16; ++j) Ls[r][cq + j] = lowb[tri + e0 + cq + j];
    } else {
        const float* diagb = Ldiag + (size_t)kc * D_SZ;
        #pragma unroll
        for (int j = 0; j < 16; ++j) {
            const int e = e0 + cq + j;
            float v = 0.f;
            if (e < d)       v = lowb[tri + e];
            else if (e == d) { float qd = diagb[d]; v = qd * qd; }
            Ls[r][cq + j] = v;
        }
    }
    __syncthreads();

    // fragment-order transposed write: d rows qp*8..+7, e = el0, el0+1
    bf16x8 p0, p1;
    #pragma unroll
    for (int j = 0; j < 8; ++j) {
        p0[j] = (__bf16)Ls[qp * 8 + j][ep * 2];
        p1[j] = (__bf16)Ls[qp * 8 + j][ep * 2 + 1];
    }
    *(bf16x8*)dst = p0;
    *(bf16x8*)(dst + 8) = p1;

    // t-partial: pt[part][e] = sum_{j} w[part*16+j] * L[part*16+j][e]
    {
        const int part = tid >> 6, ei = tid & 63;
        float sum = 0.f;
        #pragma unroll
        for (int j = 0; j < 16; ++j)
            sum += Wsm[part * 16 + j] * Ls[part * 16 + j][ei];
        pt[part][ei] = sum;
    }
    __syncthreads();
    if (tid < 64)
        tp[et * 64 + tid] = pt[0][tid] + pt[1][tid] + pt[2][tid] + pt[3][tid];
}

// ---------------------------------------------------------------------------
// K1c: t[kc][e] = sum over valid dt of tpart[kc][dt][e]
// ---------------------------------------------------------------------------
__global__ __launch_bounds__(256)
void t_reduce(const float* __restrict__ tpart, float* __restrict__ Tv) {
    const int idx = blockIdx.x * 256 + threadIdx.x;   // 131072 total
    const int kc = idx >> 9, e = idx & 511;
    const int ct = e >> 7;
    float s = 0.f;
    for (int dt = ct << 1; dt < 8; ++dt)
        s += tpart[((size_t)(kc * 8 + dt)) * 512 + e];
    Tv[idx] = s;
}

// ---------------------------------------------------------------------------
// K2: main GEMM, barrier-free K-loop. P = bf16(X) * bf16(L) from fragment
// pages via direct global->VGPR dwordx4; epilogue: rsum += (P - t[e])^2.
// ---------------------------------------------------------------------------
__device__ __forceinline__ int kch_of(int s) {
    return (s < 8) ? s : (s < 14) ? s - 6 : (s < 18) ? s - 10 : s - 12;
}

__global__ __launch_bounds__(256, 2)
void gml2_main(const __hip_bfloat16* __restrict__ Xp,
               const __hip_bfloat16* __restrict__ Bp,
               const float* __restrict__ Tv,
               float* __restrict__ Out) {
    __shared__ float osum[2][128];

    const int tid = threadIdx.x;
    const int bx  = blockIdx.x;
    // XCD swizzle: all 8 row-tiles of a class on one XCD -> pages L2-resident
    const int xcd = bx & 7;
    const int g   = bx >> 3;
    const int kc  = xcd * 32 + (g >> 3);
    const int mt  = g & 7;

    const int lane = tid & 63;
    const int wave = tid >> 6;
    const int wmg  = wave & 1;      // row 64-group
    const int wng  = wave >> 1;     // col 64-group
    const int c    = lane & 15;
    const int q    = lane >> 4;

    const __bf16* pA = (const __bf16*)Xp + (size_t)(mt * 8) * STEP_ELEMS;
    const __bf16* pB = (const __bf16*)Bp + (size_t)kc * CLASS_ELEMS;

    // per-lane byte... element offsets of the 8 fragment lines each
    int aoff[4][2], boff[4][2];
    #pragma unroll
    for (int mi = 0; mi < 4; ++mi)
        #pragma unroll
        for (int h = 0; h < 2; ++h)
            aoff[mi][h] = ((((wmg * 4 + mi) * 2 + h) * 64) + lane) * 8;
    #pragma unroll
    for (int ni = 0; ni < 4; ++ni)
        #pragma unroll
        for (int h = 0; h < 2; ++h)
            boff[ni][h] = ((((wng * 4 + ni) * 2 + h) * 64) + lane) * 8;

    f32x4 acc[4][4];
    #pragma unroll
    for (int mi = 0; mi < 4; ++mi)
        #pragma unroll
        for (int ni = 0; ni < 4; ++ni)
            acc[mi][ni] = (f32x4){0.f, 0.f, 0.f, 0.f};
    float rsum[16];
    #pragma unroll
    for (int i = 0; i < 16; ++i) rsum[i] = 0.f;

    bf16x8 fa0[4][2], fb0[4][2], fa1[4][2], fb1[4][2];

#define LOAD_A(FA, KCH) { const __bf16* p_ = pA + (KCH) * STEP_ELEMS;          \
    _Pragma("unroll") for (int mi = 0; mi < 4; ++mi)                           \
    _Pragma("unroll") for (int h = 0; h < 2; ++h)                              \
        FA[mi][h] = *(const bf16x8*)(p_ + aoff[mi][h]); }
#define LOAD_B(FB, SP) { const __bf16* p_ = pB + (SP) * STEP_ELEMS;            \
    _Pragma("unroll") for (int ni = 0; ni < 4; ++ni)                           \
    _Pragma("unroll") for (int h = 0; h < 2; ++h)                              \
        FB[ni][h] = *(const bf16x8*)(p_ + boff[ni][h]); }
#define MFMA_STEP(FA, FB)                                                      \
    _Pragma("unroll") for (int mi = 0; mi < 4; ++mi)                           \
    _Pragma("unroll") for (int ni = 0; ni < 4; ++ni)                           \
    _Pragma("unroll") for (int h = 0; h < 2; ++h)                              \
        acc[mi][ni] = __builtin_amdgcn_mfma_f32_16x16x32_bf16(                 \
            FA[mi][h], FB[ni][h], acc[mi][ni], 0, 0, 0);

    // fold: subtract t and square-accumulate; C/D layout col=c(e), row=q*4+r(b)
#define FOLD(CT) {                                                             \
    float tv_[4];                                                              \
    _Pragma("unroll") for (int ni = 0; ni < 4; ++ni)                           \
        tv_[ni] = Tv[kc * 512 + (CT) * 128 + wng * 64 + ni * 16 + c];          \
    _Pragma("unroll") for (int mi = 0; mi < 4; ++mi)                           \
    _Pragma("unroll") for (int ni = 0; ni < 4; ++ni)                           \
    _Pragma("unroll") for (int r = 0; r < 4; ++r) {                            \
        float y_ = acc[mi][ni][r] - tv_[ni];                                   \
        rsum[mi * 4 + r] += y_ * y_;                                           \
        acc[mi][ni][r] = 0.f; } }

    LOAD_A(fa0, 0); LOAD_B(fb0, 0);

    for (int s = 0; s < NSTEPS; s += 2) {
        // fold boundaries (8, 14, 18) are all even -> handled here
        if (s == 8)       { FOLD(0); }
        else if (s == 14) { FOLD(1); }
        else if (s == 18) { FOLD(2); }

        LOAD_A(fa1, kch_of(s + 1)); LOAD_B(fb1, s + 1);
        MFMA_STEP(fa0, fb0);
        if (s + 2 < NSTEPS) { LOAD_A(fa0, kch_of(s + 2)); LOAD_B(fb0, s + 2); }
        MFMA_STEP(fa1, fb1);
    }
    FOLD(3);

    // reduce the 16 e-lanes of each quad
    #pragma unroll
    for (int i = 0; i < 16; ++i) {
        float v = rsum[i];
        v += __shfl_xor(v, 1, 64);
        v += __shfl_xor(v, 2, 64);
        v += __shfl_xor(v, 4, 64);
        v += __shfl_xor(v, 8, 64);
        rsum[i] = v;
    }
    if (c == 0) {
        #pragma unroll
        for (int mi = 0; mi < 4; ++mi)
            #pragma unroll
            for (int r = 0; r < 4; ++r)
                osum[wng][wmg * 64 + mi * 16 + q * 4 + r] = rsum[mi * 4 + r];
    }
    __syncthreads();
    if (tid < 128) {
        float v = osum[0][tid] + osum[1][tid];
        Out[(size_t)(mt * 128 + tid) * KC_SZ + kc] = sqrtf(v);
    }
}

// ---------------------------------------------------------------------------
// Fallback (round-2 kernel, proven, ws-independent).
// ---------------------------------------------------------------------------
#define FLDA 40
#define BM 128
#define BN 128
__device__ __forceinline__ void fstep_map(int s, int& ct, int& k0) {
    if (s < 16)      { ct = 0; k0 = s * 32; }
    else if (s < 28) { ct = 1; k0 = 128 + (s - 16) * 32; }
    else if (s < 36) { ct = 2; k0 = 256 + (s - 28) * 32; }
    else             { ct = 3; k0 = 384 + (s - 36) * 32; }
}
__global__ __launch_bounds__(256, 2)
void gml2_fallback(const float* __restrict__ X, const float* __restrict__ W,
                   const float* __restrict__ Ldiag, const float* __restrict__ Llow,
                   float* __restrict__ Out) {
    __shared__ __bf16 As[BM * FLDA];
    __shared__ __bf16 Bs[BN * FLDA];
    __shared__ float  Ws[D_SZ];
    __shared__ float  osum[2][BM];
    const int tid = threadIdx.x;
    const int bx  = blockIdx.x;
    const int xcd = bx & 7;
    const int g   = bx >> 3;
    const int kc  = xcd * 32 + (g >> 3);
    const int mt  = g & 7;
    const int lane = tid & 63, wave = tid >> 6;
    const int wm = (wave & 1) * 64, wn = (wave >> 1) * 64;
    const int c = lane & 15, q = lane >> 4;
    const int am = tid >> 1, akh = (tid & 1) << 4;
    const float* xrow = X + (size_t)(mt * BM + am) * D_SZ;
    const float* wrow = W + (size_t)kc * D_SZ;
    const int be = tid & 127, bd = (tid >> 7) << 4;
    const float* lowbase  = Llow  + (size_t)kc * NLOW;
    const float* diagbase = Ldiag + (size_t)kc * D_SZ;
    if (tid < 128) ((f32x4*)Ws)[tid] = ((const f32x4*)wrow)[tid];
    float rsum[16];
    #pragma unroll
    for (int i = 0; i < 16; ++i) rsum[i] = 0.f;
    f32x4 acc[4][4];
    #pragma unroll
    for (int mi = 0; mi < 4; ++mi)
        #pragma unroll
        for (int ni = 0; ni < 4; ++ni) acc[mi][ni] = (f32x4){0.f, 0.f, 0.f, 0.f};
    f32x4 xr[4];
    float bb[16];
    auto prefetch = [&](int s) {
        int pct, pk0; fstep_map(s, pct, pk0);
        const int pe0 = pct * BN;
        const float* xp = xrow + pk0 + akh;
        #pragma unroll
        for (int i = 0; i < 4; ++i) xr[i] = ((const f32x4*)xp)[i];
        const int e = pe0 + be, d0 = pk0 + bd;
        int tri = (d0 * (d0 - 1)) >> 1;
        if (pk0 >= pe0 + BN) {
            #pragma unroll
            for (int j = 0; j < 16; ++j) { bb[j] = lowbase[tri + e]; tri += d0 + j; }
        } else {
            #pragma unroll
            for (int j = 0; j < 16; ++j) {
                const int d = d0 + j;
                float val = 0.f;
                if (d > e)       val = lowbase[tri + e];
                else if (d == e) { float dq = diagbase[d]; val = dq * dq; }
                bb[j] = val; tri += d;
            }
        }
    };
    prefetch(0);
    __syncthreads();
    int cur_ct = 0;
    for (int s = 0; s < 40; ++s) {
        int ct, k0; fstep_map(s, ct, k0);
        if (ct != cur_ct) {
            #pragma unroll
            for (int mi = 0; mi < 4; ++mi)
                #pragma unroll
                for (int ni = 0; ni < 4; ++ni)
                    #pragma unroll
                    for (int r = 0; r < 4; ++r) {
                        float y = acc[mi][ni][r];
                        rsum[mi * 4 + r] += y * y;
                        acc[mi][ni][r] = 0.f;
                    }
            cur_ct = ct;
        }
        bf16x8 ap0, ap1;
        {
            const f32x4* wsp = (const f32x4*)&Ws[k0 + akh];
            #pragma unroll
            for (int i = 0; i < 4; ++i) {
                f32x4 wv = wsp[i];
                #pragma unroll
                for (int l = 0; l < 4; ++l) {
                    float v = xr[i][l] - wv[l];
                    int idx = i * 4 + l;
                    if (idx < 8) ap0[idx] = (__bf16)v;
                    else         ap1[idx - 8] = (__bf16)v;
                }
            }
        }
        bf16x8 bp0, bp1;
        #pragma unroll
        for (int j = 0; j < 8; ++j) { bp0[j] = (__bf16)bb[j]; bp1[j] = (__bf16)bb[j + 8]; }
        __syncthreads();
        *(bf16x8*)&As[am * FLDA + akh]     = ap0;
        *(bf16x8*)&As[am * FLDA + akh + 8] = ap1;
        *(bf16x8*)&Bs[be * FLDA + bd]      = bp0;
        *(bf16x8*)&Bs[be * FLDA + bd + 8]  = bp1;
        if (s + 1 < 40) prefetch(s + 1);
        __syncthreads();
        bf16x8 af[4], bfr[4];
        #pragma unroll
        for (int mi = 0; mi < 4; ++mi)
            af[mi] = *(const bf16x8*)&As[(wm + mi * 16 + c) * FLDA + q * 8];
        #pragma unroll
        for (int ni = 0; ni < 4; ++ni)
            bfr[ni] = *(const bf16x8*)&Bs[(wn + ni * 16 + c) * FLDA + q * 8];
        #pragma unroll
        for (int mi = 0; mi < 4; ++mi)
            #pragma unroll
            for (int ni = 0; ni < 4; ++ni)
                acc[mi][ni] = __builtin_amdgcn_mfma_f32_16x16x32_bf16(
                    af[mi], bfr[ni], acc[mi][ni], 0, 0, 0);
    }
    #pragma unroll
    for (int mi = 0; mi < 4; ++mi)
        #pragma unroll
        for (int ni = 0; ni < 4; ++ni)
            #pragma unroll
            for (int r = 0; r < 4; ++r) {
                float y = acc[mi][ni][r];
                rsum[mi * 4 + r] += y * y;
            }
    #pragma unroll
    for (int i = 0; i < 16; ++i) {
        float s = rsum[i];
        s += __shfl_xor(s, 1, 64);
        s += __shfl_xor(s, 2, 64);
        s += __shfl_xor(s, 4, 64);
        s += __shfl_xor(s, 8, 64);
        rsum[i] = s;
    }
    const int wnIdx = wave >> 1;
    if (c == 0) {
        #pragma unroll
        for (int mi = 0; mi < 4; ++mi)
            #pragma unroll
            for (int r = 0; r < 4; ++r)
                osum[wnIdx][wm + mi * 16 + q * 4 + r] = rsum[mi * 4 + r];
    }
    __syncthreads();
    if (tid < BM) {
        float s = osum[0][tid] + osum[1][tid];
        Out[(size_t)(mt * BM + tid) * KC_SZ + kc] = sqrtf(s);
    }
}

extern "C" void kernel_launch(void* const* d_in, const int* in_sizes, int n_in,
                              void* d_out, int out_size, void* d_ws, size_t ws_size,
                              hipStream_t stream) {
    const float* X  = (const float*)d_in[0];   // [1024, 512]
    const float* W  = (const float*)d_in[1];   // [256, 1, 512]
    const float* Ld = (const float*)d_in[2];   // [256, 512]
    const float* Ll = (const float*)d_in[3];   // [256, 130816]
    float* Out = (float*)d_out;                // [1024, 256]

    if (ws_size >= WS_NEED) {
        __hip_bfloat16* Bp    = (__hip_bfloat16*)d_ws;
        __hip_bfloat16* Xp    = (__hip_bfloat16*)((char*)d_ws + OFF_XP);
        float*          tpart = (float*)((char*)d_ws + OFF_TPART);
        float*          Tvv   = (float*)((char*)d_ws + OFF_T);
        prep_x  <<<dim3(64),            dim3(256), 0, stream>>>(X, Xp);
        prep_b  <<<dim3(KC_SZ * 64),    dim3(256), 0, stream>>>(Ld, Ll, W, Bp, tpart);
        t_reduce<<<dim3(512),           dim3(256), 0, stream>>>(tpart, Tvv);
        gml2_main<<<dim3(KC_SZ * 8),    dim3(256), 0, stream>>>(Xp, Bp, Tvv, Out);
    } else {
        gml2_fallback<<<dim3(KC_SZ * 8), dim3(256), 0, stream>>>(X, W, Ld, Ll, Out);
    }
}